// Round 4
// baseline (582.042 us; speedup 1.0000x reference)
//
#include <hip/hip_runtime.h>

#define B_ 16
#define NQ 2048
#define NK 2048
#define DH 128
#define INV 0.08838834764831843f              // 1/sqrt(128)
#define QSCALE (0.08838834764831843f * 1.4426950408889634f)  // INV*log2(e), folded into Q

typedef __attribute__((ext_vector_type(8))) short bf16x8;
typedef __attribute__((ext_vector_type(4))) float f32x4;

typedef const __attribute__((address_space(1))) unsigned int* gas1_t;
typedef __attribute__((address_space(3))) unsigned int* las3_t;

#define VMW(n)   asm volatile("s_waitcnt vmcnt(" #n ")" ::: "memory")
#define BARRIER() do { __builtin_amdgcn_s_barrier(); asm volatile("" ::: "memory"); } while (0)

__device__ __forceinline__ unsigned short f2b(float f) {
  unsigned u = __float_as_uint(f);
  u += 0x7fff + ((u >> 16) & 1);          // RNE
  return (unsigned short)(u >> 16);
}

// async 16B global->LDS (DMA, no VGPR roundtrip). LDS dest must be
// wave-uniform-base + lane*16; source is per-lane (pre-swizzled).
__device__ __forceinline__ void gl_lds16(const unsigned short* g, unsigned short* l) {
  __builtin_amdgcn_global_load_lds((gas1_t)g, (las3_t)l, 16, 0, 0);
}

// ---------------- prep: fp32 -> bf16 cast with scale (q: INV*log2e, k: 1) ---
__global__ __launch_bounds__(256) void k_cvt(
    const float* __restrict__ src, unsigned short* __restrict__ dst, int n4,
    float scale) {
  int i = blockIdx.x * 256 + threadIdx.x;
  if (i >= n4) return;
  float4 f = ((const float4*)src)[i];
  ushort4 u;
  u.x = f2b(f.x * scale); u.y = f2b(f.y * scale);
  u.z = f2b(f.z * scale); u.w = f2b(f.w * scale);
  ((ushort4*)dst)[i] = u;
}

// ---------------- prep: V [b][kv][d] -> Vt bf16 [b][d][kv] ------------------
__global__ __launch_bounds__(256) void k_trans(
    const float* __restrict__ v, unsigned short* __restrict__ vt) {
  __shared__ float tile[32][33];
  const int b = blockIdx.z, kv0 = blockIdx.x << 5, d0 = blockIdx.y << 5;
  const int tx = threadIdx.x & 31, ty = threadIdx.x >> 5;
  #pragma unroll
  for (int i = 0; i < 4; i++)
    tile[ty + 8*i][tx] = v[((size_t)b*NK + kv0 + ty + 8*i)*DH + d0 + tx];
  __syncthreads();
  #pragma unroll
  for (int i = 0; i < 4; i++)
    vt[((size_t)b*DH + d0 + ty + 8*i)*NK + kv0 + tx] = f2b(tile[tx][ty + 8*i]);
}

// ---------------- fused attention -------------------------------------------
// Block: 256 thr = 4 waves; 32 q-rows; K swept in 64-col tiles (32 tiles).
// Wave (rh,nh): rh = q-row half (16 rows), nh = k-col half (32 cols).
// Q pre-scaled by INV*log2e in k_cvt -> S is already the exp2 argument.
// Sweep1: 4-tile bodies, K staged 2 TILES AHEAD (KA/VA ping-pong) and mask
//         nontemporal loads 2 tiles ahead (4 reg sets) -> issue->wait
//         distance ~2 compute phases > HBM latency. Mask bits packed into a
//         word-granular queue: static per-tile byte insert, one 7-mov
//         rotation per 4 tiles (was 14 ops/tile shift queue).
// Sweep2: r3's proven ledger verbatim (K single-buffer restaged under PV,
//         V staged at top, vmcnt(4)/vmcnt(8), normal att stores); unrolled
//         x4 only for static mask-byte extraction.
__global__ __launch_bounds__(256, 4) void k_attn(
    const unsigned short* __restrict__ qb, const unsigned short* __restrict__ kb,
    const unsigned short* __restrict__ vtb, const int* __restrict__ mask,
    float* __restrict__ att, float* __restrict__ ctx) {
  __shared__ unsigned short KA[64*128];   // 16KB
  __shared__ unsigned short VA[128*64];   // 16KB (sweep1: K buf1 / sweep2: Vt)
  __shared__ unsigned short Ps[32*64];    // 4KB
  __shared__ float Lrow[32];              // total 36992 B -> 4 blocks/CU

  const int t = threadIdx.x;
  const int wave = t >> 6, lane = t & 63, quad = lane >> 4, l15 = lane & 15;
  const int rh = wave >> 1, nh = wave & 1;

  // XCD-aware swizzle over 1024 blocks (bijective). 2 batches/XCD -> K/Vt
  // (~2MB) L2-resident for sweep2 restage.
  const int p = blockIdx.x + (blockIdx.y << 6);
  const int lid = ((p & 7) << 7) + (p >> 3);
  const int b = lid >> 6, q0 = (lid & 63) << 5;

  const unsigned short* qg = qb  + ((size_t)b*NQ + q0)*DH;
  const unsigned short* kg = kb  + (size_t)b*NK*DH;
  const unsigned short* vg = vtb + (size_t)b*DH*NK;
  const int* mg   = mask + ((size_t)b*NQ + q0)*NK;
  float*     attg = att  + ((size_t)b*NQ + q0)*NK;
  float*     cg   = ctx  + ((size_t)b*NQ + q0)*DH;

  if (t < 32) Lrow[t] = 0.f;

  // ---- Q fragments hoisted to registers (16 VGPR, loaded once) ----
  bf16x8 qf[4];
  { const unsigned short* qr = qg + (size_t)(rh*16 + l15)*DH + quad*8;
    #pragma unroll
    for (int kd = 0; kd < 4; kd++) qf[kd] = *(const bf16x8*)(qr + kd*32); }

  const int row0 = rh*16 + quad*4;
  const int* mgR[4]; float* attR[4];
  #pragma unroll
  for (int r = 0; r < 4; r++) {
    mgR[r]  = mg   + (size_t)(row0 + r)*NK + nh*32 + l15;
    attR[r] = attg + (size_t)(row0 + r)*NK + nh*32 + l15;
  }

  // swizzled byte-base offsets: addr = base ^ cb (cb 16B-aligned, < row size)
  const int kr0 = nh*32 + l15, kr1 = kr0 + 16;
  const int kbs0 = (kr0 << 8) ^ ((kr0 & 7) << 4);
  const int kbs1 = (kr1 << 8) ^ ((kr1 & 7) << 4);
  const int pr  = rh*16 + l15;
  const int pbs = (pr << 7) ^ ((pr & 7) << 4);
  int vbs[4];
  #pragma unroll
  for (int dt = 0; dt < 4; dt++) {
    int d = nh*64 + dt*16 + l15;
    vbs[dt] = (d << 7) ^ ((d & 7) << 4);
  }

  auto stageK = [&](unsigned short* buf, const unsigned short* src) {
    #pragma unroll
    for (int i = 0; i < 4; i++) {
      int L = (wave << 12) + (i << 10) + (lane << 4);   // lds byte offset
      int row = L >> 8;
      int cb  = (L & 255) ^ ((row & 7) << 4);
      gl_lds16(src + ((size_t)row << 7) + (cb >> 1), buf + (L >> 1));
    }
  };
  auto stageV = [&](const unsigned short* src) {   // src = vg + k0
    #pragma unroll
    for (int i = 0; i < 4; i++) {
      int L = (wave << 12) + (i << 10) + (lane << 4);
      int d  = L >> 7;
      int cb = (L & 127) ^ ((d & 7) << 4);
      gl_lds16(src + (size_t)d*NK + (cb >> 1), VA + (L >> 1));
    }
  };
  auto loadMask = [&](int k0, int* mr) {   // 8 nontemporal dword loads
    #pragma unroll
    for (int nt = 0; nt < 2; nt++)
      #pragma unroll
      for (int r = 0; r < 4; r++)
        mr[nt*4 + r] = __builtin_nontemporal_load(mgR[r] + k0 + nt*16);
  };
  auto qkt = [&](const unsigned short* buf, f32x4& s0v, f32x4& s1v) {
    s0v = 0; s1v = 0;
    const char* bc = (const char*)buf;
    __builtin_amdgcn_s_setprio(1);
    #pragma unroll
    for (int kd = 0; kd < 4; kd++) {
      int cb = (kd*32 + quad*8) << 1;
      bf16x8 b0 = *(const bf16x8*)(bc + (kbs0 ^ cb));
      bf16x8 b1 = *(const bf16x8*)(bc + (kbs1 ^ cb));
      s0v = __builtin_amdgcn_mfma_f32_16x16x32_bf16(qf[kd], b0, s0v, 0, 0, 0);
      s1v = __builtin_amdgcn_mfma_f32_16x16x32_bf16(qf[kd], b1, s1v, 0, 0, 0);
    }
    __builtin_amdgcn_s_setprio(0);
  };

  float ls[4] = {0.f, 0.f, 0.f, 0.f};

  // exp2 (Q pre-scaled), mask-bit return. Adds into ls.
  auto epi1 = [&](const int* mr, const f32x4& s0v, const f32x4& s1v) -> unsigned {
    unsigned nb = 0;
    #pragma unroll
    for (int nt = 0; nt < 2; nt++) {
      const f32x4& sv = nt ? s1v : s0v;
      #pragma unroll
      for (int r = 0; r < 4; r++) {
        float e = __builtin_amdgcn_exp2f(sv[r]);
        if (mr[nt*4 + r] != 0) { nb |= 1u << (nt*4 + r); e = 0.f; }
        ls[r] += e;
      }
    }
    return nb;
  };

  // word-granular mask queue: word i = tiles 4i..4i+3 (byte per tile)
  unsigned mw0=0,mw1=0,mw2=0,mw3=0,mw4=0,mw5=0,mw6=0,mw7=0;

  // ================= sweep 1: 4-tile bodies, 2-tile-ahead prefetch ==========
  // Ledger: groups of 12 (stage4+mask8) per tile; at each wait exactly 2
  // groups outstanding -> vmcnt(12) completes the consumed tile's group,
  // issued 2 tiles (~2 compute phases) earlier.
  int mrA[8], mrB[8], mrC[8], mrD[8];
  stageK(KA, kg);                 loadMask(0,    mrA);
  stageK(VA, kg + (size_t)64*DH); loadMask(64,   mrB);

#define S1_STEP(RDBUF, MR, SH, VN) do {                                  \
    VMW(VN); BARRIER();                                                  \
    f32x4 s0, s1; qkt(RDBUF, s0, s1);                                    \
    bw |= epi1(MR, s0, s1) << SH;                                        \
    BARRIER(); } while (0)

  for (int t2 = 0; t2 < 28; t2 += 4) {
    unsigned bw = 0;
    S1_STEP(KA, mrA, 0, 12);
    stageK(KA, kg + (size_t)(t2+2)*64*DH); loadMask((t2+2)*64, mrC);
    S1_STEP(VA, mrB, 8, 12);
    stageK(VA, kg + (size_t)(t2+3)*64*DH); loadMask((t2+3)*64, mrD);
    S1_STEP(KA, mrC, 16, 12);
    stageK(KA, kg + (size_t)(t2+4)*64*DH); loadMask((t2+4)*64, mrA);
    S1_STEP(VA, mrD, 24, 12);
    stageK(VA, kg + (size_t)(t2+5)*64*DH); loadMask((t2+5)*64, mrB);
    mw0=mw1; mw1=mw2; mw2=mw3; mw3=mw4; mw4=mw5; mw5=mw6; mw6=mw7; mw7=bw;
  }
  { // tail: tiles 28..31 (no issues past 31; final drain)
    unsigned bw = 0;
    S1_STEP(KA, mrA, 0, 12);
    stageK(KA, kg + (size_t)30*64*DH); loadMask(30*64, mrC);
    S1_STEP(VA, mrB, 8, 12);
    stageK(VA, kg + (size_t)31*64*DH); loadMask(31*64, mrD);
    S1_STEP(KA, mrC, 16, 12);
    S1_STEP(VA, mrD, 24, 0);
    mw0=mw1; mw1=mw2; mw2=mw3; mw3=mw4; mw4=mw5; mw5=mw6; mw6=mw7; mw7=bw;
  }
#undef S1_STEP

  // ================= row-sum reduction (shfl pre-reduce, 1 atomic/wave) =====
  __syncthreads();
  #pragma unroll
  for (int r = 0; r < 4; r++) {
    float v = ls[r];
    v += __shfl_xor(v, 1); v += __shfl_xor(v, 2);
    v += __shfl_xor(v, 4); v += __shfl_xor(v, 8);
    if (l15 == 0) atomicAdd(&Lrow[row0 + r], v);
  }
  __syncthreads();
  float il[4];
  #pragma unroll
  for (int r = 0; r < 4; r++) il[r] = 1.0f / Lrow[row0 + r];

  f32x4 ca[4];
  #pragma unroll
  for (int dt = 0; dt < 4; dt++) ca[dt] = 0;

  // ================= sweep 2: att + ctx (r3 ledger verbatim) ================
  // at top: inflight = [att st 8][K 4] + issue V4 -> vmcnt(4) = K done.
  // after epi: inflight = [V 4][att st 8] -> vmcnt(8) = V done.
  stageK(KA, kg);
  for (int t4 = 0; t4 < 32; t4 += 4) {
    unsigned cw = mw0;
    mw0=mw1; mw1=mw2; mw2=mw3; mw3=mw4; mw4=mw5; mw5=mw6; mw6=mw7;
    #pragma unroll
    for (int k = 0; k < 4; k++) {
      const int tt = t4 + k;
      BARRIER();                    // PV(tt-1) done -> VA writable
      stageV(vg + tt*64);
      VMW(4);                       // K(tt) in LDS
      BARRIER();
      f32x4 s0, s1;
      qkt(KA, s0, s1);

      const unsigned nb = (cw >> (8*k)) & 255u;   // k static (unrolled)
      #pragma unroll
      for (int nt = 0; nt < 2; nt++) {
        const f32x4& sv = nt ? s1 : s0;
        #pragma unroll
        for (int r = 0; r < 4; r++) {
          float e = __builtin_amdgcn_exp2f(sv[r]) * il[r];
          if ((nb >> (nt*4 + r)) & 1) e = 0.f;
          attR[r][tt*64 + nt*16] = e;      // normal store (L2 write-merge)
          int row = row0 + r;
          int cbw = ((nh*32 + nt*16 + l15) << 1) ^ ((row & 7) << 4);
          *(unsigned short*)((char*)Ps + (row << 7) + cbw) = f2b(e);
        }
      }
      asm volatile("s_waitcnt vmcnt(8) lgkmcnt(0)" ::: "memory"); // V done, Ps flushed
      BARRIER();                    // Ps visible to all waves
      if (tt + 1 < 32) stageK(KA, kg + (size_t)(tt+1)*64*DH);  // hides under PV

      __builtin_amdgcn_s_setprio(1);
      #pragma unroll
      for (int kv = 0; kv < 2; kv++) {
        int cb = (kv*32 + quad*8) << 1;
        bf16x8 pa = *(const bf16x8*)((const char*)Ps + (pbs ^ cb));
        #pragma unroll
        for (int dt = 0; dt < 4; dt++) {
          bf16x8 vb = *(const bf16x8*)((const char*)VA + (vbs[dt] ^ cb));
          ca[dt] = __builtin_amdgcn_mfma_f32_16x16x32_bf16(pa, vb, ca[dt], 0, 0, 0);
        }
      }
      __builtin_amdgcn_s_setprio(0);
    }
  }

  #pragma unroll
  for (int dt = 0; dt < 4; dt++)
    #pragma unroll
    for (int r = 0; r < 4; r++)
      cg[(size_t)(row0 + r)*DH + nh*64 + dt*16 + l15] = ca[dt][r];
}

extern "C" void kernel_launch(void* const* d_in, const int* in_sizes, int n_in,
                              void* d_out, int out_size, void* d_ws, size_t ws_size,
                              hipStream_t stream) {
  const float* q = (const float*)d_in[0];
  const float* k = (const float*)d_in[1];
  const float* v = (const float*)d_in[2];
  const int* mask = (const int*)d_in[3];
  float* ctx = (float*)d_out;
  float* att = ctx + (size_t)B_*NQ*DH;

  const size_t NE = (size_t)B_*NQ*DH;
  unsigned short* qws = (unsigned short*)d_ws;
  unsigned short* kws = qws + NE;
  unsigned short* vws = kws + NE;

  k_cvt  <<<(int)(NE/1024), 256, 0, stream>>>(q, qws, (int)(NE/4), QSCALE);
  k_cvt  <<<(int)(NE/1024), 256, 0, stream>>>(k, kws, (int)(NE/4), 1.0f);
  k_trans<<<dim3(NK/32, DH/32, B_), 256, 0, stream>>>(v, vws);
  k_attn <<<dim3(NQ/32, B_), 256, 0, stream>>>(qws, kws, vws, mask, att, ctx);
}

// Round 5
// 568.683 us; speedup vs baseline: 1.0235x; 1.0235x over previous
//
#include <hip/hip_runtime.h>

#define B_ 16
#define NQ 2048
#define NK 2048
#define DH 128
#define QSCALE (0.08838834764831843f * 1.4426950408889634f)  // 1/sqrt(128)*log2e

typedef __attribute__((ext_vector_type(8))) short bf16x8;
typedef __attribute__((ext_vector_type(4))) float f32x4;

typedef const __attribute__((address_space(1))) unsigned int* gas1_t;
typedef __attribute__((address_space(3))) unsigned int* las3_t;

#define VMW(n)   asm volatile("s_waitcnt vmcnt(" #n ")" ::: "memory")
#define BARRIER() do { __builtin_amdgcn_s_barrier(); asm volatile("" ::: "memory"); } while (0)

__device__ __forceinline__ unsigned short f2b(float f) {
  unsigned u = __float_as_uint(f);
  u += 0x7fff + ((u >> 16) & 1);          // RNE
  return (unsigned short)(u >> 16);
}

// async 16B global->LDS (DMA). LDS dest = wave-uniform base + lane*16.
__device__ __forceinline__ void gl_lds16(const unsigned short* g, unsigned short* l) {
  __builtin_amdgcn_global_load_lds((gas1_t)g, (las3_t)l, 16, 0, 0);
}

// ---------------- prep: fp32 -> bf16 cast with scale (q: INV*log2e, k: 1) ---
__global__ __launch_bounds__(256) void k_cvt(
    const float* __restrict__ src, unsigned short* __restrict__ dst, int n4,
    float scale) {
  int i = blockIdx.x * 256 + threadIdx.x;
  if (i >= n4) return;
  float4 f = ((const float4*)src)[i];
  ushort4 u;
  u.x = f2b(f.x * scale); u.y = f2b(f.y * scale);
  u.z = f2b(f.z * scale); u.w = f2b(f.w * scale);
  ((ushort4*)dst)[i] = u;
}

// ---------------- prep: V [b][kv][d] -> Vt bf16 [b][d][kv] ------------------
__global__ __launch_bounds__(256) void k_trans(
    const float* __restrict__ v, unsigned short* __restrict__ vt) {
  __shared__ float tile[32][33];
  const int b = blockIdx.z, kv0 = blockIdx.x << 5, d0 = blockIdx.y << 5;
  const int tx = threadIdx.x & 31, ty = threadIdx.x >> 5;
  #pragma unroll
  for (int i = 0; i < 4; i++)
    tile[ty + 8*i][tx] = v[((size_t)b*NK + kv0 + ty + 8*i)*DH + d0 + tx];
  __syncthreads();
  #pragma unroll
  for (int i = 0; i < 4; i++)
    vt[((size_t)b*DH + d0 + ty + 8*i)*NK + kv0 + tx] = f2b(tile[tx][ty + 8*i]);
}

// ---------------- fused attention -------------------------------------------
// Block: 256 thr = 4 waves; 32 q-rows; K swept in 64-col tiles (32 tiles).
// Wave (rh,nh): rh = q-row half (16 rows), nh = k-col half (32 cols).
// Q pre-scaled by INV*log2e -> S is the exp2 argument directly.
// Sweep1: r3's proven ledger (KA/KB ping-pong, stage t+1 per step, vmcnt(12),
//         2 mask reg sets, nontemporal mask loads). Mask bits -> word queue
//         (static byte insert per step, one rotation per 4 tiles).
// Sweep2: K DOUBLE-BUFFERED (r5 change). K(t+1) issued at tile top ->
//         consumed after a full tile (~600cy cover vs r3's ~150cy).
//         Ledger/wave: ...V(t-1)4 K(t)4 st8 | V(t)4 K(t+1)4... ->
//         vmcnt(16) completes K(t); vmcnt(12) after epi completes V(t).
//         Tile 31 restages tile 0 (dummy) to keep ledger uniform.
// LDS 53.4KB -> 3 blocks/CU (trade occupancy for pipeline depth).
__global__ __launch_bounds__(256, 4) void k_attn(
    const unsigned short* __restrict__ qb, const unsigned short* __restrict__ kb,
    const unsigned short* __restrict__ vtb, const int* __restrict__ mask,
    float* __restrict__ att, float* __restrict__ ctx) {
  __shared__ unsigned short KA[64*128];   // 16KB  K buf0 (both sweeps)
  __shared__ unsigned short KB[64*128];   // 16KB  K buf1 (both sweeps)
  __shared__ unsigned short VA[128*64];   // 16KB  sweep2 Vt[d][kv]
  __shared__ unsigned short Ps[32*64];    // 4KB
  __shared__ float Lrow[32];              // total 53376 B -> 3 blocks/CU

  const int t = threadIdx.x;
  const int wave = t >> 6, lane = t & 63, quad = lane >> 4, l15 = lane & 15;
  const int rh = wave >> 1, nh = wave & 1;

  // XCD-aware swizzle over 1024 blocks (bijective). 2 batches/XCD -> K/Vt
  // (~2MB) L2-resident for sweep2 restage.
  const int p = blockIdx.x + (blockIdx.y << 6);
  const int lid = ((p & 7) << 7) + (p >> 3);
  const int b = lid >> 6, q0 = (lid & 63) << 5;

  const unsigned short* qg = qb  + ((size_t)b*NQ + q0)*DH;
  const unsigned short* kg = kb  + (size_t)b*NK*DH;
  const unsigned short* vg = vtb + (size_t)b*DH*NK;
  const int* mg   = mask + ((size_t)b*NQ + q0)*NK;
  float*     attg = att  + ((size_t)b*NQ + q0)*NK;
  float*     cg   = ctx  + ((size_t)b*NQ + q0)*DH;

  if (t < 32) Lrow[t] = 0.f;

  // ---- Q fragments hoisted to registers (16 VGPR, loaded once) ----
  bf16x8 qf[4];
  { const unsigned short* qr = qg + (size_t)(rh*16 + l15)*DH + quad*8;
    #pragma unroll
    for (int kd = 0; kd < 4; kd++) qf[kd] = *(const bf16x8*)(qr + kd*32); }

  const int row0 = rh*16 + quad*4;
  const int* mgR[4]; float* attR[4];
  #pragma unroll
  for (int r = 0; r < 4; r++) {
    mgR[r]  = mg   + (size_t)(row0 + r)*NK + nh*32 + l15;
    attR[r] = attg + (size_t)(row0 + r)*NK + nh*32 + l15;
  }

  // swizzled byte-base offsets: addr = base ^ cb (cb 16B-aligned, < row size)
  const int kr0 = nh*32 + l15, kr1 = kr0 + 16;
  const int kbs0 = (kr0 << 8) ^ ((kr0 & 7) << 4);
  const int kbs1 = (kr1 << 8) ^ ((kr1 & 7) << 4);
  const int pr  = rh*16 + l15;
  const int pbs = (pr << 7) ^ ((pr & 7) << 4);
  int vbs[4];
  #pragma unroll
  for (int dt = 0; dt < 4; dt++) {
    int d = nh*64 + dt*16 + l15;
    vbs[dt] = (d << 7) ^ ((d & 7) << 4);
  }

  auto stageK = [&](unsigned short* buf, const unsigned short* src) {
    #pragma unroll
    for (int i = 0; i < 4; i++) {
      int L = (wave << 12) + (i << 10) + (lane << 4);   // lds byte offset
      int row = L >> 8;
      int cb  = (L & 255) ^ ((row & 7) << 4);
      gl_lds16(src + ((size_t)row << 7) + (cb >> 1), buf + (L >> 1));
    }
  };
  auto stageV = [&](const unsigned short* src) {   // src = vg + k0
    #pragma unroll
    for (int i = 0; i < 4; i++) {
      int L = (wave << 12) + (i << 10) + (lane << 4);
      int d  = L >> 7;
      int cb = (L & 127) ^ ((d & 7) << 4);
      gl_lds16(src + (size_t)d*NK + (cb >> 1), VA + (L >> 1));
    }
  };
  auto loadMask = [&](int k0, int* mr) {   // 8 nontemporal dword loads
    #pragma unroll
    for (int nt = 0; nt < 2; nt++)
      #pragma unroll
      for (int r = 0; r < 4; r++)
        mr[nt*4 + r] = __builtin_nontemporal_load(mgR[r] + k0 + nt*16);
  };
  auto qkt = [&](const unsigned short* buf, f32x4& s0v, f32x4& s1v) {
    s0v = 0; s1v = 0;
    const char* bc = (const char*)buf;
    __builtin_amdgcn_s_setprio(1);
    #pragma unroll
    for (int kd = 0; kd < 4; kd++) {
      int cb = (kd*32 + quad*8) << 1;
      bf16x8 b0 = *(const bf16x8*)(bc + (kbs0 ^ cb));
      bf16x8 b1 = *(const bf16x8*)(bc + (kbs1 ^ cb));
      s0v = __builtin_amdgcn_mfma_f32_16x16x32_bf16(qf[kd], b0, s0v, 0, 0, 0);
      s1v = __builtin_amdgcn_mfma_f32_16x16x32_bf16(qf[kd], b1, s1v, 0, 0, 0);
    }
    __builtin_amdgcn_s_setprio(0);
  };

  float ls[4] = {0.f, 0.f, 0.f, 0.f};

  auto epi1 = [&](const int* mr, const f32x4& s0v, const f32x4& s1v) -> unsigned {
    unsigned nb = 0;
    #pragma unroll
    for (int nt = 0; nt < 2; nt++) {
      const f32x4& sv = nt ? s1v : s0v;
      #pragma unroll
      for (int r = 0; r < 4; r++) {
        float e = __builtin_amdgcn_exp2f(sv[r]);
        if (mr[nt*4 + r] != 0) { nb |= 1u << (nt*4 + r); e = 0.f; }
        ls[r] += e;
      }
    }
    return nb;
  };

  // word-granular mask queue: word i = tiles 4i..4i+3 (byte per tile)
  unsigned mw0=0,mw1=0,mw2=0,mw3=0,mw4=0,mw5=0,mw6=0,mw7=0;

  // ================= sweep 1: r3 ledger (1-ahead, vmcnt(12)) ================
  int mrA[8], mrB[8];
  stageK(KA, kg);
  loadMask(0, mrA);

  // step T: BARRIER; stage K(T+1)->other buf; loadMask(T+1); VMW(12);
  //         BARRIER; qkt(buf[T&1]); epi -> byte (T&3) of bw.
#define S1_STEP(T, RD, WR, MRC, MRN, VN) do {                            \
    BARRIER();                                                           \
    if ((T) + 1 < 32) {                                                  \
      stageK(WR, kg + (size_t)((T)+1)*64*DH);                            \
      loadMask(((T)+1)*64, MRN);                                         \
    }                                                                    \
    VMW(VN); BARRIER();                                                  \
    f32x4 s0, s1; qkt(RD, s0, s1);                                       \
    bw |= epi1(MRC, s0, s1) << (8*((T)&3)); } while (0)

  for (int t2 = 0; t2 < 28; t2 += 4) {
    unsigned bw = 0;
    S1_STEP(t2+0, KA, KB, mrA, mrB, 12);
    S1_STEP(t2+1, KB, KA, mrB, mrA, 12);
    S1_STEP(t2+2, KA, KB, mrA, mrB, 12);
    S1_STEP(t2+3, KB, KA, mrB, mrA, 12);
    mw0=mw1; mw1=mw2; mw2=mw3; mw3=mw4; mw4=mw5; mw5=mw6; mw6=mw7; mw7=bw;
  }
  { unsigned bw = 0;
    S1_STEP(28, KA, KB, mrA, mrB, 12);
    S1_STEP(29, KB, KA, mrB, mrA, 12);
    S1_STEP(30, KA, KB, mrA, mrB, 12);
    S1_STEP(31, KB, KA, mrB, mrA, 0);
    mw0=mw1; mw1=mw2; mw2=mw3; mw3=mw4; mw4=mw5; mw5=mw6; mw6=mw7; mw7=bw;
  }
#undef S1_STEP

  // pre-stage sweep2's K(0) -> KA; overlaps the Lrow reduction below.
  stageK(KA, kg);

  // ================= row-sum reduction (shfl pre-reduce, 1 atomic/wave) =====
  __syncthreads();
  #pragma unroll
  for (int r = 0; r < 4; r++) {
    float v = ls[r];
    v += __shfl_xor(v, 1); v += __shfl_xor(v, 2);
    v += __shfl_xor(v, 4); v += __shfl_xor(v, 8);
    if (l15 == 0) atomicAdd(&Lrow[row0 + r], v);
  }
  __syncthreads();
  float il[4];
  #pragma unroll
  for (int r = 0; r < 4; r++) il[r] = 1.0f / Lrow[row0 + r];

  f32x4 ca[4];
  #pragma unroll
  for (int dt = 0; dt < 4; dt++) ca[dt] = 0;

  VMW(0);   // own K(0) stage complete (issued pre-reduction: usually free)

  // ================= sweep 2: K double-buffered, deep ledger ================
  for (int t4 = 0; t4 < 32; t4 += 4) {
    unsigned cw = mw0;
    mw0=mw1; mw1=mw2; mw2=mw3; mw3=mw4; mw4=mw5; mw5=mw6; mw6=mw7;
    #pragma unroll
    for (int k = 0; k < 4; k++) {
      const int tt = t4 + k;
      BARRIER();                        // #1: PV(tt-1) done -> VA writable;
                                        //     all waves' K stages issued
      stageV(vg + tt*64);
      stageK((tt & 1) ? KA : KB,        // K(tt+1) -> other buf (full-tile cover)
             kg + (size_t)((tt + 1) & 31)*64*DH);   // tt=31: dummy restage of 0
      VMW(16);                          // K(tt) resident (see ledger)
      BARRIER();                        // #2: all waves have K(tt)
      f32x4 s0, s1;
      qkt((tt & 1) ? KB : KA, s0, s1);

      const unsigned nb = (cw >> (8*k)) & 255u;   // k static (unrolled)
      #pragma unroll
      for (int nt = 0; nt < 2; nt++) {
        const f32x4& sv = nt ? s1 : s0;
        #pragma unroll
        for (int r = 0; r < 4; r++) {
          float e = __builtin_amdgcn_exp2f(sv[r]) * il[r];
          if ((nb >> (nt*4 + r)) & 1) e = 0.f;
          attR[r][tt*64 + nt*16] = e;   // normal store (L2 write-merge, r2 A/B)
          int row = row0 + r;
          int cbw = ((nh*32 + nt*16 + l15) << 1) ^ ((row & 7) << 4);
          *(unsigned short*)((char*)Ps + (row << 7) + cbw) = f2b(e);
        }
      }
      asm volatile("s_waitcnt vmcnt(12) lgkmcnt(0)" ::: "memory"); // V(tt) done,
      BARRIER();                        // #3: Ps + V visible to all waves
      __builtin_amdgcn_s_setprio(1);
      #pragma unroll
      for (int kv = 0; kv < 2; kv++) {
        int cb = (kv*32 + quad*8) << 1;
        bf16x8 pa = *(const bf16x8*)((const char*)Ps + (pbs ^ cb));
        #pragma unroll
        for (int dt = 0; dt < 4; dt++) {
          bf16x8 vb = *(const bf16x8*)((const char*)VA + (vbs[dt] ^ cb));
          ca[dt] = __builtin_amdgcn_mfma_f32_16x16x32_bf16(pa, vb, ca[dt], 0, 0, 0);
        }
      }
      __builtin_amdgcn_s_setprio(0);
    }
  }

  #pragma unroll
  for (int dt = 0; dt < 4; dt++)
    #pragma unroll
    for (int r = 0; r < 4; r++)
      cg[(size_t)(row0 + r)*DH + nh*64 + dt*16 + l15] = ca[dt][r];
}

extern "C" void kernel_launch(void* const* d_in, const int* in_sizes, int n_in,
                              void* d_out, int out_size, void* d_ws, size_t ws_size,
                              hipStream_t stream) {
  const float* q = (const float*)d_in[0];
  const float* k = (const float*)d_in[1];
  const float* v = (const float*)d_in[2];
  const int* mask = (const int*)d_in[3];
  float* ctx = (float*)d_out;
  float* att = ctx + (size_t)B_*NQ*DH;

  const size_t NE = (size_t)B_*NQ*DH;
  unsigned short* qws = (unsigned short*)d_ws;
  unsigned short* kws = qws + NE;
  unsigned short* vws = kws + NE;

  k_cvt  <<<(int)(NE/1024), 256, 0, stream>>>(q, qws, (int)(NE/4), QSCALE);
  k_cvt  <<<(int)(NE/1024), 256, 0, stream>>>(k, kws, (int)(NE/4), 1.0f);
  k_trans<<<dim3(NK/32, DH/32, B_), 256, 0, stream>>>(v, vws);
  k_attn <<<dim3(NQ/32, B_), 256, 0, stream>>>(qws, kws, vws, mask, att, ctx);
}

// Round 6
// 537.377 us; speedup vs baseline: 1.0831x; 1.0583x over previous
//
#include <hip/hip_runtime.h>

#define B_ 16
#define NQ 2048
#define NK 2048
#define DH 128
#define QSCALE (0.08838834764831843f * 1.4426950408889634f)  // 1/sqrt(128)*log2e

typedef __attribute__((ext_vector_type(8))) short bf16x8;
typedef __attribute__((ext_vector_type(4))) float f32x4;

typedef const __attribute__((address_space(1))) unsigned int* gas1_t;
typedef __attribute__((address_space(3))) unsigned int* las3_t;

#define VMW(n)   asm volatile("s_waitcnt vmcnt(" #n ")" ::: "memory")
#define BARRIER() do { __builtin_amdgcn_s_barrier(); asm volatile("" ::: "memory"); } while (0)

__device__ __forceinline__ unsigned short f2b(float f) {
  unsigned u = __float_as_uint(f);
  u += 0x7fff + ((u >> 16) & 1);          // RNE
  return (unsigned short)(u >> 16);
}

// async 16B global->LDS (DMA). LDS dest = wave-uniform base + lane*16.
__device__ __forceinline__ void gl_lds16(const unsigned short* g, unsigned short* l) {
  __builtin_amdgcn_global_load_lds((gas1_t)g, (las3_t)l, 16, 0, 0);
}

// ---------------- prep: fp32 -> bf16 cast with scale (q: INV*log2e, k: 1) ---
__global__ __launch_bounds__(256) void k_cvt(
    const float* __restrict__ src, unsigned short* __restrict__ dst, int n4,
    float scale) {
  int i = blockIdx.x * 256 + threadIdx.x;
  if (i >= n4) return;
  float4 f = ((const float4*)src)[i];
  ushort4 u;
  u.x = f2b(f.x * scale); u.y = f2b(f.y * scale);
  u.z = f2b(f.z * scale); u.w = f2b(f.w * scale);
  ((ushort4*)dst)[i] = u;
}

// ---------------- prep: V [b][kv][d] -> Vt bf16 [b][d][kv] ------------------
__global__ __launch_bounds__(256) void k_trans(
    const float* __restrict__ v, unsigned short* __restrict__ vt) {
  __shared__ float tile[32][33];
  const int b = blockIdx.z, kv0 = blockIdx.x << 5, d0 = blockIdx.y << 5;
  const int tx = threadIdx.x & 31, ty = threadIdx.x >> 5;
  #pragma unroll
  for (int i = 0; i < 4; i++)
    tile[ty + 8*i][tx] = v[((size_t)b*NK + kv0 + ty + 8*i)*DH + d0 + tx];
  __syncthreads();
  #pragma unroll
  for (int i = 0; i < 4; i++)
    vt[((size_t)b*DH + d0 + ty + 8*i)*NK + kv0 + tx] = f2b(tile[tx][ty + 8*i]);
}

// ---------------- fused attention -------------------------------------------
// Block: 512 thr = 8 waves; 64 q-rows; K swept in 64-col tiles (32 tiles).
// Wave (rh,nh): rh = q-row group (16 rows, 0..3), nh = k-col half (32 cols).
// Q pre-scaled by INV*log2e -> S is the exp2 argument directly.
// ALL vmem a full tile ahead (r6): sweep1 K+mask 1-ahead (vmcnt(10));
// sweep2 K AND V double-buffered, G(t+1)={K2,V2} issued at tile-t top,
// vmcnt(12) completes G(t) [ledger: G(t)4, st(t-1)8, G(t+1)4]. The only
// intra-tile wait is lgkmcnt(0) on the Ps LDS roundtrip.
// Grid 512 blocks = 2/CU co-resident (LDS 74KB), 16 waves/CU.
__global__ __launch_bounds__(512, 4) void k_attn(
    const unsigned short* __restrict__ qb, const unsigned short* __restrict__ kb,
    const unsigned short* __restrict__ vtb, const int* __restrict__ mask,
    float* __restrict__ att, float* __restrict__ ctx) {
  __shared__ unsigned short KA[64*128];   // 16KB  K buf0
  __shared__ unsigned short KB[64*128];   // 16KB  K buf1
  __shared__ unsigned short VA[128*64];   // 16KB  Vt buf0 [d][kv]
  __shared__ unsigned short VB[128*64];   // 16KB  Vt buf1
  __shared__ unsigned short Ps[64*64];    // 8KB
  __shared__ float Lrow[64];              // total 73984 B -> 2 blocks/CU

  const int t = threadIdx.x;
  const int wave = t >> 6, lane = t & 63, quad = lane >> 4, l15 = lane & 15;
  const int rh = wave >> 1, nh = wave & 1;

  // XCD-aware swizzle over 512 blocks (bijective). 64 blocks/XCD -> 2
  // batches/XCD -> K/Vt (~2MB) L2-resident.
  const int p = blockIdx.x + (blockIdx.y << 5);
  const int lid = ((p & 7) << 6) + (p >> 3);
  const int b = lid >> 5, q0 = (lid & 31) << 6;

  const unsigned short* qg = qb  + ((size_t)b*NQ + q0)*DH;
  const unsigned short* kg = kb  + (size_t)b*NK*DH;
  const unsigned short* vg = vtb + (size_t)b*DH*NK;
  const int* mg   = mask + ((size_t)b*NQ + q0)*NK;
  float*     attg = att  + ((size_t)b*NQ + q0)*NK;
  float*     cg   = ctx  + ((size_t)b*NQ + q0)*DH;

  if (t < 64) Lrow[t] = 0.f;

  // ---- Q fragments hoisted to registers (16 VGPR, loaded once) ----
  bf16x8 qf[4];
  { const unsigned short* qr = qg + (size_t)(rh*16 + l15)*DH + quad*8;
    #pragma unroll
    for (int kd = 0; kd < 4; kd++) qf[kd] = *(const bf16x8*)(qr + kd*32); }

  const int row0 = rh*16 + quad*4;
  const int* mgR[4]; float* attR[4];
  #pragma unroll
  for (int r = 0; r < 4; r++) {
    mgR[r]  = mg   + (size_t)(row0 + r)*NK + nh*32 + l15;
    attR[r] = attg + (size_t)(row0 + r)*NK + nh*32 + l15;
  }

  // swizzled byte-base offsets: addr = base ^ cb (cb 16B-aligned, < row size)
  const int kr0 = nh*32 + l15, kr1 = kr0 + 16;
  const int kbs0 = (kr0 << 8) ^ ((kr0 & 7) << 4);
  const int kbs1 = (kr1 << 8) ^ ((kr1 & 7) << 4);
  const int pr  = rh*16 + l15;
  const int pbs = (pr << 7) ^ ((pr & 7) << 4);
  int vbs[4];
  #pragma unroll
  for (int dt = 0; dt < 4; dt++) {
    int d = nh*64 + dt*16 + l15;
    vbs[dt] = (d << 7) ^ ((d & 7) << 4);
  }

  // stage 64x128-ush K tile (16KB): 512 thr x 2 x 16B. LDS linear dest;
  // SOURCE pre-swizzled so LDS[row*256 + (cb^((row&7)<<4))] = K[row][cb/2].
  auto stageK = [&](unsigned short* buf, const unsigned short* src) {
    #pragma unroll
    for (int i = 0; i < 2; i++) {
      int L = (i << 13) + (t << 4);     // lds byte offset
      int row = L >> 8;
      int cb  = (L & 255) ^ ((row & 7) << 4);
      gl_lds16(src + ((size_t)row << 7) + (cb >> 1), buf + (L >> 1));
    }
  };
  auto stageV = [&](unsigned short* buf, const unsigned short* src) { // src=vg+k0
    #pragma unroll
    for (int i = 0; i < 2; i++) {
      int L = (i << 13) + (t << 4);
      int d  = L >> 7;
      int cb = (L & 127) ^ ((d & 7) << 4);
      gl_lds16(src + (size_t)d*NK + (cb >> 1), buf + (L >> 1));
    }
  };
  auto loadMask = [&](int k0, int* mr) {   // 8 nontemporal dword loads
    #pragma unroll
    for (int nt = 0; nt < 2; nt++)
      #pragma unroll
      for (int r = 0; r < 4; r++)
        mr[nt*4 + r] = __builtin_nontemporal_load(mgR[r] + k0 + nt*16);
  };
  auto qkt = [&](const unsigned short* buf, f32x4& s0v, f32x4& s1v) {
    s0v = 0; s1v = 0;
    const char* bc = (const char*)buf;
    __builtin_amdgcn_s_setprio(1);
    #pragma unroll
    for (int kd = 0; kd < 4; kd++) {
      int cb = (kd*32 + quad*8) << 1;
      bf16x8 b0 = *(const bf16x8*)(bc + (kbs0 ^ cb));
      bf16x8 b1 = *(const bf16x8*)(bc + (kbs1 ^ cb));
      s0v = __builtin_amdgcn_mfma_f32_16x16x32_bf16(qf[kd], b0, s0v, 0, 0, 0);
      s1v = __builtin_amdgcn_mfma_f32_16x16x32_bf16(qf[kd], b1, s1v, 0, 0, 0);
    }
    __builtin_amdgcn_s_setprio(0);
  };

  float ls[4] = {0.f, 0.f, 0.f, 0.f};

  auto epi1 = [&](const int* mr, const f32x4& s0v, const f32x4& s1v) -> unsigned {
    unsigned nb = 0;
    #pragma unroll
    for (int nt = 0; nt < 2; nt++) {
      const f32x4& sv = nt ? s1v : s0v;
      #pragma unroll
      for (int r = 0; r < 4; r++) {
        float e = __builtin_amdgcn_exp2f(sv[r]);
        if (mr[nt*4 + r] != 0) { nb |= 1u << (nt*4 + r); e = 0.f; }
        ls[r] += e;
      }
    }
    return nb;
  };

  // word-granular mask queue: word i = tiles 4i..4i+3 (byte per tile)
  unsigned mw0=0,mw1=0,mw2=0,mw3=0,mw4=0,mw5=0,mw6=0,mw7=0;

  // ================= sweep 1: 1-ahead ledger, vmcnt(10) =====================
  // Per wave per tile: stage 2 + mask 8 = 10 ops; at the wait exactly 2
  // groups outstanding -> vmcnt(10) completes the consumed tile's group.
  int mrA[8], mrB[8];
  stageK(KA, kg);
  loadMask(0, mrA);

#define S1_STEP(T, RD, WR, MRC, MRN, VN) do {                            \
    BARRIER();                                                           \
    if ((T) + 1 < 32) {                                                  \
      stageK(WR, kg + (size_t)((T)+1)*64*DH);                            \
      loadMask(((T)+1)*64, MRN);                                         \
    }                                                                    \
    VMW(VN); BARRIER();                                                  \
    f32x4 s0, s1; qkt(RD, s0, s1);                                       \
    bw |= epi1(MRC, s0, s1) << (8*((T)&3)); } while (0)

  for (int t2 = 0; t2 < 28; t2 += 4) {
    unsigned bw = 0;
    S1_STEP(t2+0, KA, KB, mrA, mrB, 10);
    S1_STEP(t2+1, KB, KA, mrB, mrA, 10);
    S1_STEP(t2+2, KA, KB, mrA, mrB, 10);
    S1_STEP(t2+3, KB, KA, mrB, mrA, 10);
    mw0=mw1; mw1=mw2; mw2=mw3; mw3=mw4; mw4=mw5; mw5=mw6; mw6=mw7; mw7=bw;
  }
  { unsigned bw = 0;
    S1_STEP(28, KA, KB, mrA, mrB, 10);
    S1_STEP(29, KB, KA, mrB, mrA, 10);
    S1_STEP(30, KA, KB, mrA, mrB, 10);
    S1_STEP(31, KB, KA, mrB, mrA, 0);
    mw0=mw1; mw1=mw2; mw2=mw3; mw3=mw4; mw4=mw5; mw5=mw6; mw6=mw7; mw7=bw;
  }
#undef S1_STEP

  // pre-stage sweep2 G(0) = {K(0)->KA, V(0)->VA}: overlaps the reduction.
  stageK(KA, kg);
  stageV(VA, vg);

  // ================= row-sum reduction (shfl pre-reduce, 1 atomic/wave) =====
  __syncthreads();
  #pragma unroll
  for (int r = 0; r < 4; r++) {
    float v = ls[r];
    v += __shfl_xor(v, 1); v += __shfl_xor(v, 2);
    v += __shfl_xor(v, 4); v += __shfl_xor(v, 8);
    if (l15 == 0) atomicAdd(&Lrow[row0 + r], v);
  }
  __syncthreads();
  float il[4];
  #pragma unroll
  for (int r = 0; r < 4; r++) il[r] = 1.0f / Lrow[row0 + r];

  f32x4 ca[4];
  #pragma unroll
  for (int dt = 0; dt < 4; dt++) ca[dt] = 0;

  VMW(0);   // own G(0) portion complete (issued pre-reduction: mostly hidden)

  // ================= sweep 2: K+V double-buffered, full-tile-ahead ==========
  for (int t4 = 0; t4 < 32; t4 += 4) {
    unsigned cw = mw0;
    mw0=mw1; mw1=mw2; mw2=mw3; mw3=mw4; mw4=mw5; mw5=mw6; mw6=mw7;
    #pragma unroll
    for (int k = 0; k < 4; k++) {
      const int tt = t4 + k;
      BARRIER();                        // B1: PV(tt-1) readers done -> bufs
                                        //     of parity (tt+1)&1 writable
      { const int nx = (tt + 1) & 31;   // tt=31: dummy restage of tile 0
        stageK((tt & 1) ? KA : KB, kg + (size_t)nx*64*DH);
        stageV((tt & 1) ? VA : VB, vg + nx*64);
      }
      VMW(12);                          // G(tt) resident (G(tt)4,st8,G(tt+1)4)
      BARRIER();                        // B2: all waves' G(tt) portions in LDS
      f32x4 s0, s1;
      qkt((tt & 1) ? KB : KA, s0, s1);

      const unsigned nb = (cw >> (8*k)) & 255u;   // k static (unrolled)
      #pragma unroll
      for (int nt = 0; nt < 2; nt++) {
        const f32x4& sv = nt ? s1 : s0;
        #pragma unroll
        for (int r = 0; r < 4; r++) {
          float e = __builtin_amdgcn_exp2f(sv[r]) * il[r];
          if ((nb >> (nt*4 + r)) & 1) e = 0.f;
          attR[r][tt*64 + nt*16] = e;   // normal store (L2 write-merge, r2 A/B)
          int row = row0 + r;
          int cbw = ((nh*32 + nt*16 + l15) << 1) ^ ((row & 7) << 4);
          *(unsigned short*)((char*)Ps + (row << 7) + cbw) = f2b(e);
        }
      }
      asm volatile("s_waitcnt lgkmcnt(0)" ::: "memory");  // Ps writes flushed
      BARRIER();                        // B3: Ps visible to all waves
      __builtin_amdgcn_s_setprio(1);
      const char* vbuf = (const char*)((tt & 1) ? VB : VA);
      #pragma unroll
      for (int kv = 0; kv < 2; kv++) {
        int cb = (kv*32 + quad*8) << 1;
        bf16x8 pa = *(const bf16x8*)((const char*)Ps + (pbs ^ cb));
        #pragma unroll
        for (int dt = 0; dt < 4; dt++) {
          bf16x8 vb = *(const bf16x8*)(vbuf + (vbs[dt] ^ cb));
          ca[dt] = __builtin_amdgcn_mfma_f32_16x16x32_bf16(pa, vb, ca[dt], 0, 0, 0);
        }
      }
      __builtin_amdgcn_s_setprio(0);
    }
  }

  #pragma unroll
  for (int dt = 0; dt < 4; dt++)
    #pragma unroll
    for (int r = 0; r < 4; r++)
      cg[(size_t)(row0 + r)*DH + nh*64 + dt*16 + l15] = ca[dt][r];
}

extern "C" void kernel_launch(void* const* d_in, const int* in_sizes, int n_in,
                              void* d_out, int out_size, void* d_ws, size_t ws_size,
                              hipStream_t stream) {
  const float* q = (const float*)d_in[0];
  const float* k = (const float*)d_in[1];
  const float* v = (const float*)d_in[2];
  const int* mask = (const int*)d_in[3];
  float* ctx = (float*)d_out;
  float* att = ctx + (size_t)B_*NQ*DH;

  const size_t NE = (size_t)B_*NQ*DH;
  unsigned short* qws = (unsigned short*)d_ws;
  unsigned short* kws = qws + NE;
  unsigned short* vws = kws + NE;

  k_cvt  <<<(int)(NE/1024), 256, 0, stream>>>(q, qws, (int)(NE/4), QSCALE);
  k_cvt  <<<(int)(NE/1024), 256, 0, stream>>>(k, kws, (int)(NE/4), 1.0f);
  k_trans<<<dim3(NK/32, DH/32, B_), 256, 0, stream>>>(v, vws);
  k_attn <<<dim3(NQ/64, B_), 512, 0, stream>>>(qws, kws, vws, mask, att, ctx);
}